// Round 8
// baseline (91388.855 us; speedup 1.0000x reference)
//
#include <hip/hip_runtime.h>
#include <cstdint>
#include <cstddef>

#define H        2048
#define T_STEPS  16384
#define G        256       // grid: 256 WGs (2 rails x 128 chunks), 1 WG/CU
#define NCHUNK   128       // h partitioned into 128 chunks of 16
#define WGSIZE   256
#define NSLOT    8         // slot rotation: step s -> slot s&7
#define RAILSZ   8192      // dwords per rail = 8 slots * 1024 dwords
#define SENT     0x7FFF7FFFu
#define SENT64   0x7FFF7FFF7FFF7FFFull

// dynamic LDS sized to force 1 WG/CU (160 KiB pool); actual use ~9 KB
#define LDS_DYN_BYTES 90112
// carve-out offsets (bytes) inside dynamic LDS
#define LDS_H16_OFF  0          // uint32 h16s[2][1024] transposed f16x2 = 8 KB
#define LDS_GC_OFF   8192       // float4 gc[48]
#define LDS_RED_OFF  8960       // float red[4]

typedef unsigned long long ull;
typedef unsigned int uv4 __attribute__((ext_vector_type(4)));
typedef _Float16 half2_ __attribute__((ext_vector_type(2)));

__device__ __forceinline__ float sigmoidf_(float x) {
    return 1.0f / (1.0f + __expf(-x));
}
__device__ __forceinline__ float tanhf_(float x) {
    return 1.0f - 2.0f / (__expf(2.0f * x) + 1.0f);
}
__device__ __forceinline__ uint32_t pack_f16x2(float a, float b) {
    _Float16 ha = (_Float16)a, hb = (_Float16)b;
    return (uint32_t)__builtin_bit_cast(uint16_t, ha)
         | ((uint32_t)__builtin_bit_cast(uint16_t, hb) << 16);
}
__device__ __forceinline__ float f16lo(uint32_t d) {
    return (float)__builtin_bit_cast(_Float16, (uint16_t)(d & 0xFFFFu));
}
__device__ __forceinline__ float f16hi(uint32_t d) {
    return (float)__builtin_bit_cast(_Float16, (uint16_t)(d >> 16));
}
__device__ __forceinline__ float dot2f(uint32_t w, uint32_t h, float acc) {
#if __has_builtin(__builtin_amdgcn_fdot2)
    return __builtin_amdgcn_fdot2(__builtin_bit_cast(half2_, w),
                                  __builtin_bit_cast(half2_, h), acc, false);
#else
    return acc + f16lo(w) * f16lo(h) + f16hi(w) * f16hi(h);
#endif
}
__device__ __forceinline__ void st_agent_u64(ull* p, ull v) {
    __hip_atomic_store(p, v, __ATOMIC_RELAXED, __HIP_MEMORY_SCOPE_AGENT);
}
__device__ __forceinline__ void st_agent_u32(uint32_t* p, uint32_t v) {
    __hip_atomic_store(p, v, __ATOMIC_RELAXED, __HIP_MEMORY_SCOPE_AGENT);
}

// slab: [2 rails][8 slots][1024 dwords f16x2] = 64 KB.
// slot 0 of both rails = h(0) = zeros; others sentinel.
__global__ void init_slab_kernel(uint32_t* __restrict__ hs) {
    int i = blockIdx.x * 256 + threadIdx.x;       // 0..16383
    int in_rail = i & (RAILSZ - 1);
    st_agent_u32(hs + i, (in_rail < 1024) ? 0u : SENT);
}

extern "C" __global__ void __launch_bounds__(WGSIZE, 1)
gru_persistent_kernel(const float* __restrict__ samples,
                      const float* __restrict__ w_ih,
                      const float* __restrict__ w_hh,
                      const float* __restrict__ b_ih,
                      const float* __restrict__ b_hh,
                      const float* __restrict__ fc_w,
                      const float* __restrict__ fc_b,
                      float* __restrict__ out,
                      uint32_t* __restrict__ slab)
{
    extern __shared__ char smem[];
    uint32_t* h16s = (uint32_t*)(smem + LDS_H16_OFF);   // [2][1024] transposed
    float4*   gc   = (float4*)(smem + LDS_GC_OFF);      // [48]
    float*    red  = (float*)(smem + LDS_RED_OFF);      // [4]

    const int g    = blockIdx.x;
    const int rail = g >> 7;        // 0 or 1: which rail this WG publishes to
    const int k    = g & 127;       // chunk id: owns h[16k .. 16k+16)
    const int tid  = threadIdx.x;
    const int wave = tid >> 6;      // 4 waves; wave owns h[16k+4*wave .. +4)
    const int lane = tid & 63;

    // ---- one-time: 12 weight rows per wave -> 192 f16x2 dwords per LANE ----
    // lane l holds h-columns [32l, 32l+32) of each of its wave's 12 rows.
    uint32_t wreg[12][16];
#pragma unroll
    for (int q = 0; q < 12; ++q) {
        int gate = q >> 2, jj = q & 3;
        int row  = gate * H + k * 16 + wave * 4 + jj;
        const float* src = w_hh + (size_t)row * H + lane * 32;
#pragma unroll
        for (int b = 0; b < 8; ++b) {
            float4 f = *(const float4*)(src + b * 4);
            wreg[q][2 * b]     = pack_f16x2(f.x, f.y);
            wreg[q][2 * b + 1] = pack_f16x2(f.z, f.w);
        }
    }
    if (tid < 48) {
        int w = tid / 12, q = tid % 12;
        int gate = q >> 2, jj = q & 3;
        int row  = gate * H + k * 16 + w * 4 + jj;
        gc[tid] = make_float4(w_ih[2 * row], w_ih[2 * row + 1], b_ih[row], b_hh[row]);
    }
    __syncthreads();

    float hloc[4] = {0.f, 0.f, 0.f, 0.f};   // this wave's 4 owned h (lane 0)

    // ---- 16384 sequential steps; one barrier per step ----
    for (int t = 0; t < T_STEPS; ++t) {
        float2 sv = *(const float2*)(samples + 2 * (size_t)t);
        const int p = t & 1;
        const int s = t & 7;

        if (tid < 128) {
            // thread i polls chunk i's 32B line on BOTH rails; granule (8B,
            // one wave's 4 h) is valid on a rail iff its lead dword != SENT.
            // Accept per-granule min(rail0, rail1) — values are bit-identical.
            const uint32_t* r0 = slab + (s << 10) + tid * 8;
            const uint32_t* r1 = r0 + RAILSZ;
            uint32_t m[8];
            for (;;) {
                uv4 a0, a1, b0, b1;
                asm volatile(
                    "global_load_dwordx4 %0, %4, off sc0 sc1\n\t"
                    "global_load_dwordx4 %1, %4, off offset:16 sc0 sc1\n\t"
                    "global_load_dwordx4 %2, %5, off sc0 sc1\n\t"
                    "global_load_dwordx4 %3, %5, off offset:16 sc0 sc1\n\t"
                    "s_waitcnt vmcnt(0)"
                    : "=v"(a0), "=v"(a1), "=v"(b0), "=v"(b1)
                    : "v"(r0), "v"(r1)
                    : "memory");
                uint32_t A[8] = {a0.x, a0.y, a0.z, a0.w, a1.x, a1.y, a1.z, a1.w};
                uint32_t B[8] = {b0.x, b0.y, b0.z, b0.w, b1.x, b1.y, b1.z, b1.w};
                bool ok = true;
#pragma unroll
                for (int c = 0; c < 4; ++c) {
                    bool av = (A[2 * c] != SENT);
                    m[2 * c]     = av ? A[2 * c]     : B[2 * c];
                    m[2 * c + 1] = av ? A[2 * c + 1] : B[2 * c + 1];
                    ok &= (av | (B[2 * c] != SENT));
                }
                if (ok) break;
                __builtin_amdgcn_s_sleep(2);
            }
            // stage transposed: h-dword d -> LDS idx ((d&15)<<6)|(d>>4)
            // so compute reads are bank-conflict-free (2-way only).
#pragma unroll
            for (int c = 0; c < 8; ++c) {
                int dlow = 8 * (tid & 1) + c;
                h16s[p * 1024 + (dlow << 6) + (tid >> 1)] = m[c];
            }
        }
        __syncthreads();   // the only barrier: h16s[p] complete

        // lane l reads its 16 h-dwords (h elements 32l..32l+31)
        uint32_t hreg[16];
#pragma unroll
        for (int j = 0; j < 16; ++j)
            hreg[j] = h16s[p * 1024 + (j << 6) + lane];

        float acc[12];
#pragma unroll
        for (int q = 0; q < 12; ++q) {
            float ssum = 0.f;
#pragma unroll
            for (int j = 0; j < 16; ++j)
                ssum = dot2f(wreg[q][j], hreg[j], ssum);
            acc[q] = ssum;
        }
#pragma unroll
        for (int off = 32; off > 0; off >>= 1) {
#pragma unroll
            for (int q = 0; q < 12; ++q)
                acc[q] += __shfl_xor(acc[q], off, 64);
        }

        if (lane == 0) {
            float hn[4];
#pragma unroll
            for (int jj = 0; jj < 4; ++jj) {
                float4 cr = gc[wave * 12 + jj];
                float4 cz = gc[wave * 12 + 4 + jj];
                float4 cn = gc[wave * 12 + 8 + jj];
                float xr = sv.x * cr.x + sv.y * cr.y + cr.z;
                float xz = sv.x * cz.x + sv.y * cz.y + cz.z;
                float xn = sv.x * cn.x + sv.y * cn.y + cn.z;
                float r = sigmoidf_(xr + acc[jj]     + cr.w);
                float z = sigmoidf_(xz + acc[4 + jj] + cz.w);
                float n = tanhf_(xn + r * (acc[8 + jj] + cn.w));
                hn[jj] = (1.0f - z) * n + z * hloc[jj];
                hloc[jj] = hn[jj];
            }
            // publish step t+1 (one 8B granule on our rail), fire-and-forget
            ull pk = (ull)pack_f16x2(hn[0], hn[1])
                   | ((ull)pack_f16x2(hn[2], hn[3]) << 32);
            uint32_t* base = slab + rail * RAILSZ;
            st_agent_u64((ull*)(base + (((t + 1) & 7) << 10) + k * 8 + wave * 2), pk);
            // re-sentinel our own granule in the slot that will carry t+5
            // (written by us at step t+4; readers of its old data are >=2
            // steps clear by the skew<=1 bound)
            st_agent_u64((ull*)(base + (((t + 5) & 7) << 10) + k * 8 + wave * 2), SENT64);
        }
        // no end-of-step barrier: next step stages into the other parity
    }

    // ---- epilogue: WG 0 computes sigmoid(h_T . fc_w + fc_b) ----
    if (g == 0) {
        float part = 0.f;
        if (tid < 128) {
            // h(16384) lives in slot 16384&7 = 0
            const uint32_t* r0 = slab + tid * 8;
            const uint32_t* r1 = r0 + RAILSZ;
            uint32_t m[8];
            for (;;) {
                uv4 a0, a1, b0, b1;
                asm volatile(
                    "global_load_dwordx4 %0, %4, off sc0 sc1\n\t"
                    "global_load_dwordx4 %1, %4, off offset:16 sc0 sc1\n\t"
                    "global_load_dwordx4 %2, %5, off sc0 sc1\n\t"
                    "global_load_dwordx4 %3, %5, off offset:16 sc0 sc1\n\t"
                    "s_waitcnt vmcnt(0)"
                    : "=v"(a0), "=v"(a1), "=v"(b0), "=v"(b1)
                    : "v"(r0), "v"(r1)
                    : "memory");
                uint32_t A[8] = {a0.x, a0.y, a0.z, a0.w, a1.x, a1.y, a1.z, a1.w};
                uint32_t B[8] = {b0.x, b0.y, b0.z, b0.w, b1.x, b1.y, b1.z, b1.w};
                bool ok = true;
#pragma unroll
                for (int c = 0; c < 4; ++c) {
                    bool av = (A[2 * c] != SENT);
                    m[2 * c]     = av ? A[2 * c]     : B[2 * c];
                    m[2 * c + 1] = av ? A[2 * c + 1] : B[2 * c + 1];
                    ok &= (av | (B[2 * c] != SENT));
                }
                if (ok) break;
                __builtin_amdgcn_s_sleep(2);
            }
            const float* fw = fc_w + tid * 16;
#pragma unroll
            for (int c = 0; c < 8; ++c)
                part += f16lo(m[c]) * fw[2 * c] + f16hi(m[c]) * fw[2 * c + 1];
        }
#pragma unroll
        for (int off = 32; off > 0; off >>= 1)
            part += __shfl_xor(part, off, 64);
        if (lane == 0) red[wave] = part;
        __syncthreads();
        if (tid == 0)
            out[0] = sigmoidf_(red[0] + red[1] + red[2] + red[3] + fc_b[0]);
    }
}

extern "C" void kernel_launch(void* const* d_in, const int* in_sizes, int n_in,
                              void* d_out, int out_size, void* d_ws, size_t ws_size,
                              hipStream_t stream) {
    const float* samples = (const float*)d_in[0];
    const float* w_ih    = (const float*)d_in[1];
    const float* w_hh    = (const float*)d_in[2];
    const float* b_ih    = (const float*)d_in[3];
    const float* b_hh    = (const float*)d_in[4];
    const float* fc_w    = (const float*)d_in[5];
    const float* fc_b    = (const float*)d_in[6];
    float*    out  = (float*)d_out;
    uint32_t* slab = (uint32_t*)d_ws;    // [2][8][1024] dwords = 64 KB

    hipLaunchKernelGGL(init_slab_kernel, dim3(64), dim3(256), 0, stream, slab);

    hipFuncSetAttribute((const void*)gru_persistent_kernel,
                        hipFuncAttributeMaxDynamicSharedMemorySize, LDS_DYN_BYTES);

    void* args[] = {(void*)&samples, (void*)&w_ih, (void*)&w_hh, (void*)&b_ih,
                    (void*)&b_hh, (void*)&fc_w, (void*)&fc_b,
                    (void*)&out, (void*)&slab};
    hipError_t rc = hipLaunchCooperativeKernel(
        reinterpret_cast<void*>(gru_persistent_kernel),
        dim3(G), dim3(WGSIZE), args, LDS_DYN_BYTES, stream);
    if (rc != hipSuccess) {
        hipLaunchKernelGGL(gru_persistent_kernel, dim3(G), dim3(WGSIZE), LDS_DYN_BYTES,
                           stream, samples, w_ih, w_hh, b_ih, b_hh, fc_w, fc_b, out, slab);
    }
}

// Round 9
// 60856.506 us; speedup vs baseline: 1.5017x; 1.5017x over previous
//
#include <hip/hip_runtime.h>
#include <cstdint>
#include <cstddef>

#define H        2048
#define T_STEPS  16384
#define G        256     // workgroups == CUs, 1 WG/CU
#define HC       8       // h indices per WG (H/G)
#define NROW     24      // 3 gates * HC rows of w_hh per WG
#define WGSIZE   256
#define NREP     8       // mailbox replicas: reader WG g polls replica g&7

// LDS layout (bytes)
#define LDS_W_OFF    0                        // f16 weights: 24 rows * 2048 cols * 2B = 96KB
#define LDS_H16_OFF  98304                    // uint32 h16[2][1024] packed f16x2 = 8KB
#define LDS_GC_OFF   (98304 + 8192)           // float4 gc[24]: (wi0, wi1, b_ih, b_hh)
#define LDS_RED_OFF  (98304 + 8192 + 384)     // float red[8]
#define LDS_BYTES    (98304 + 8192 + 384 + 32)

typedef unsigned long long ull;
typedef unsigned int uv4 __attribute__((ext_vector_type(4)));
typedef _Float16 half2_ __attribute__((ext_vector_type(2)));

__device__ __forceinline__ float sigmoidf_(float x) {
    return 1.0f / (1.0f + __expf(-x));
}
__device__ __forceinline__ float tanhf_(float x) {
    return 1.0f - 2.0f / (__expf(2.0f * x) + 1.0f);
}
__device__ __forceinline__ uint32_t pack_f16x2(float a, float b) {
    _Float16 ha = (_Float16)a, hb = (_Float16)b;
    return (uint32_t)__builtin_bit_cast(uint16_t, ha)
         | ((uint32_t)__builtin_bit_cast(uint16_t, hb) << 16);
}
__device__ __forceinline__ float f16lo(uint32_t d) {
    return (float)__builtin_bit_cast(_Float16, (uint16_t)(d & 0xFFFFu));
}
__device__ __forceinline__ float f16hi(uint32_t d) {
    return (float)__builtin_bit_cast(_Float16, (uint16_t)(d >> 16));
}
__device__ __forceinline__ float dot2f(uint32_t w, uint32_t h, float acc) {
#if __has_builtin(__builtin_amdgcn_fdot2)
    return __builtin_amdgcn_fdot2(__builtin_bit_cast(half2_, w),
                                  __builtin_bit_cast(half2_, h), acc, false);
#else
    return acc + f16lo(w) * f16lo(h) + f16hi(w) * f16hi(h);
#endif
}
// relaxed agent-scope atomics: bypass non-coherent L2, no fence instructions
__device__ __forceinline__ void st_agent_u64(ull* p, ull v) {
    __hip_atomic_store(p, v, __ATOMIC_RELAXED, __HIP_MEMORY_SCOPE_AGENT);
}

// hrep layout: [8 replicas][2 parities][1024 slots of {f16x2, u32 tag}] = 128KB
__global__ void init_hrep_kernel(ull* __restrict__ hl) {
    int i = blockIdx.x * 256 + threadIdx.x;            // 0..16383
    int parity = (i >> 10) & 1;
    // parity 0 of every replica: h=(0,0) tagged 0 (the t=0 state); parity 1: invalid.
    ull v = (parity == 0) ? 0ull : 0xFFFFFFFF00000000ull;
    __hip_atomic_store(hl + i, v, __ATOMIC_RELAXED, __HIP_MEMORY_SCOPE_AGENT);
}

extern "C" __global__ void __launch_bounds__(WGSIZE, 1)
gru_persistent_kernel(const float* __restrict__ samples,
                      const float* __restrict__ w_ih,
                      const float* __restrict__ w_hh,
                      const float* __restrict__ b_ih,
                      const float* __restrict__ b_hh,
                      const float* __restrict__ fc_w,
                      const float* __restrict__ fc_b,
                      float* __restrict__ out,
                      ull*   __restrict__ hrep)    // [8][2][1024] tagged slots
{
    extern __shared__ char smem[];
    uint32_t* wlds = (uint32_t*)(smem + LDS_W_OFF);    // f16x2 dwords, row stride 1024
    uint32_t* h16s = (uint32_t*)(smem + LDS_H16_OFF);  // [2][1024]
    float4*   gc   = (float4*)(smem + LDS_GC_OFF);
    float*    red  = (float*)(smem + LDS_RED_OFF);

    const int g    = blockIdx.x;
    const int tid  = threadIdx.x;
    const int wave = tid >> 6;
    const int lane = tid & 63;
    const int myrep = g & (NREP - 1);   // the replica this WG reads

    // ---- one-time: stage this WG's 24 w_hh rows into LDS as f16 ----
    for (int rho = 0; rho < NROW; ++rho) {
        int w_r  = rho / 6;
        int rem  = rho - 6 * w_r;
        int gate = rem >> 1;
        int jj   = rem & 1;
        int grow = gate * H + g * HC + 2 * w_r + jj;
        const float* src = w_hh + (size_t)grow * H + tid * 8;
        float4 a = *(const float4*)(src);
        float4 b = *(const float4*)(src + 4);
        uint4 p;
        p.x = pack_f16x2(a.x, a.y);
        p.y = pack_f16x2(a.z, a.w);
        p.z = pack_f16x2(b.x, b.y);
        p.w = pack_f16x2(b.z, b.w);
        *(uint4*)(wlds + rho * 1024 + tid * 4) = p;
    }
    if (tid < NROW) {
        int rho  = tid;
        int w_r  = rho / 6;
        int rem  = rho - 6 * w_r;
        int gate = rem >> 1;
        int jj   = rem & 1;
        int grow = gate * H + g * HC + 2 * w_r + jj;
        gc[rho] = make_float4(w_ih[grow * 2 + 0], w_ih[grow * 2 + 1], b_ih[grow], b_hh[grow]);
    }
    __syncthreads();

    // this wave's two owned h values, kept in f32 registers (lane 0 uses them)
    float hloc0 = 0.0f, hloc1 = 0.0f;

    // ---- 16384 sequential steps; ONE barrier per step ----
    for (int t = 0; t < T_STEPS; ++t) {
        float2 sv = *(const float2*)(samples + 2 * (size_t)t);
        const int p = t & 1;

        // poll OUR REPLICA's 4 slots for WG tid (32B: 8 h + 4 tags) until tags==t.
        // Replication cuts readers-per-line 256 -> 32: the MALL slice queue per
        // line shrinks 8x, and publish stores no longer sit behind reader backlog.
        const ull* lp = hrep + ((size_t)(myrep * 2 + p) << 10) + tid * 4;
        const uint32_t tu = (uint32_t)t;
        uv4 q0, q1;
        for (;;) {
            asm volatile(
                "global_load_dwordx4 %0, %2, off sc0 sc1\n\t"
                "global_load_dwordx4 %1, %2, off offset:16 sc0 sc1\n\t"
                "s_waitcnt vmcnt(0)"
                : "=v"(q0), "=v"(q1)
                : "v"(lp)
                : "memory");
            if ((q0.y == tu) & (q0.w == tu) & (q1.y == tu) & (q1.w == tu)) break;
            __builtin_amdgcn_s_sleep(2);
        }
        // stage the 4 f16x2 pairs into this parity's LDS buffer (one b128 write)
        uint4 hw;
        hw.x = q0.x; hw.y = q0.z; hw.z = q1.x; hw.w = q1.z;
        *(uint4*)(h16s + p * 1024 + tid * 4) = hw;
        __syncthreads();   // the only barrier: h16s[p] complete before compute

        // lane l consumes chunks {l, l+64, l+128, l+192}; 16B per chunk (8 f16)
        uint4 hq[4];
#pragma unroll
        for (int k = 0; k < 4; ++k)
            hq[k] = *(const uint4*)(h16s + p * 1024 + (lane + 64 * k) * 4);

        float acc[6];
#pragma unroll
        for (int qi = 0; qi < 6; ++qi) {
            const uint32_t* wrow = wlds + (wave * 6 + qi) * 1024;
            float s = 0.0f;
#pragma unroll
            for (int k = 0; k < 4; ++k) {
                uint4 wv = *(const uint4*)(wrow + (lane + 64 * k) * 4);
                s = dot2f(wv.x, hq[k].x, s);
                s = dot2f(wv.y, hq[k].y, s);
                s = dot2f(wv.z, hq[k].z, s);
                s = dot2f(wv.w, hq[k].w, s);
            }
            acc[qi] = s;
        }
#pragma unroll
        for (int off = 32; off > 0; off >>= 1) {
#pragma unroll
            for (int qi = 0; qi < 6; ++qi)
                acc[qi] += __shfl_xor(acc[qi], off, 64);
        }

        if (lane == 0) {
            float hn2[2];
            float hold[2] = {hloc0, hloc1};
#pragma unroll
            for (int jj = 0; jj < 2; ++jj) {
                float4 cr = gc[wave * 6 + jj];
                float4 cz = gc[wave * 6 + 2 + jj];
                float4 cn = gc[wave * 6 + 4 + jj];
                float xr = sv.x * cr.x + sv.y * cr.y + cr.z;
                float xz = sv.x * cz.x + sv.y * cz.y + cz.z;
                float xn = sv.x * cn.x + sv.y * cn.y + cn.z;
                float r = sigmoidf_(xr + acc[jj]     + cr.w);
                float z = sigmoidf_(xz + acc[2 + jj] + cz.w);
                float n = tanhf_(xn + r * (acc[4 + jj] + cn.w));
                hn2[jj] = (1.0f - z) * n + z * hold[jj];
            }
            hloc0 = hn2[0];
            hloc1 = hn2[1];
            // publish the tagged 8B granule to ALL 8 replicas (fire-and-forget;
            // 8 distinct lines/slices so none queues behind a hot line)
            ull s0 = (ull)pack_f16x2(hn2[0], hn2[1]) | ((ull)(uint32_t)(t + 1) << 32);
            const int pn = (t + 1) & 1;
            ull* base = hrep + g * 4 + wave;
#pragma unroll
            for (int r = 0; r < NREP; ++r)
                st_agent_u64(base + ((size_t)(r * 2 + pn) << 10), s0);
        }
        // no end-of-step barrier: next step stages into the OTHER LDS parity
    }

    // ---- epilogue: WG 0 computes sigmoid(h_T . fc_w + fc_b) ----
    if (g == 0) {
        const ull* lp = hrep + ((size_t)(T_STEPS & 1) << 10) + tid * 4;  // replica 0
        const uint32_t tu = (uint32_t)T_STEPS;
        uv4 q0, q1;
        for (;;) {
            asm volatile(
                "global_load_dwordx4 %0, %2, off sc0 sc1\n\t"
                "global_load_dwordx4 %1, %2, off offset:16 sc0 sc1\n\t"
                "s_waitcnt vmcnt(0)"
                : "=v"(q0), "=v"(q1)
                : "v"(lp)
                : "memory");
            if ((q0.y == tu) & (q0.w == tu) & (q1.y == tu) & (q1.w == tu)) break;
            __builtin_amdgcn_s_sleep(2);
        }
        float hv[8];
        hv[0] = f16lo(q0.x); hv[1] = f16hi(q0.x);
        hv[2] = f16lo(q0.z); hv[3] = f16hi(q0.z);
        hv[4] = f16lo(q1.x); hv[5] = f16hi(q1.x);
        hv[6] = f16lo(q1.z); hv[7] = f16hi(q1.z);
        float pacc = 0.0f;
#pragma unroll
        for (int e = 0; e < 8; ++e)
            pacc += hv[e] * fc_w[tid * 8 + e];
#pragma unroll
        for (int off = 32; off > 0; off >>= 1)
            pacc += __shfl_xor(pacc, off, 64);
        if (lane == 0) red[wave] = pacc;
        __syncthreads();
        if (tid == 0) {
            float s = red[0] + red[1] + red[2] + red[3];
            out[0] = sigmoidf_(s + fc_b[0]);
        }
    }
}

extern "C" void kernel_launch(void* const* d_in, const int* in_sizes, int n_in,
                              void* d_out, int out_size, void* d_ws, size_t ws_size,
                              hipStream_t stream) {
    const float* samples = (const float*)d_in[0];
    const float* w_ih    = (const float*)d_in[1];
    const float* w_hh    = (const float*)d_in[2];
    const float* b_ih    = (const float*)d_in[3];
    const float* b_hh    = (const float*)d_in[4];
    const float* fc_w    = (const float*)d_in[5];
    const float* fc_b    = (const float*)d_in[6];
    float* out  = (float*)d_out;
    ull*   hrep = (ull*)d_ws;    // [8][2][1024] tagged slots = 128KB

    // seed every replica: parity-0 = h0 (zeros, tag 0); parity-1 = sentinel
    hipLaunchKernelGGL(init_hrep_kernel, dim3(64), dim3(256), 0, stream, hrep);

    hipFuncSetAttribute((const void*)gru_persistent_kernel,
                        hipFuncAttributeMaxDynamicSharedMemorySize, LDS_BYTES);

    void* args[] = {(void*)&samples, (void*)&w_ih, (void*)&w_hh, (void*)&b_ih,
                    (void*)&b_hh, (void*)&fc_w, (void*)&fc_b,
                    (void*)&out, (void*)&hrep};
    hipError_t rc = hipLaunchCooperativeKernel(
        reinterpret_cast<void*>(gru_persistent_kernel),
        dim3(G), dim3(WGSIZE), args, LDS_BYTES, stream);
    if (rc != hipSuccess) {
        hipLaunchKernelGGL(gru_persistent_kernel, dim3(G), dim3(WGSIZE), LDS_BYTES, stream,
                           samples, w_ih, w_hh, b_ih, b_hh, fc_w, fc_b, out, hrep);
    }
}